// Round 4
// baseline (571.067 us; speedup 1.0000x reference)
//
#include <hip/hip_runtime.h>
#include <hip/hip_bf16.h>
#include <hip/hip_cooperative_groups.h>
#include <math.h>

namespace cg = cooperative_groups;

// Problem constants
#define V 50257
#define E 512
#define H 1024
#define L 512
#define EH 1536

__device__ __forceinline__ float wave_reduce_sum(float v) {
    #pragma unroll
    for (int off = 32; off > 0; off >>= 1) v += __shfl_down(v, off, 64);
    return v;
}

// ---------------------------------------------------------------------------
// Fused persistent front-end (cooperative): phases A-D with grid.sync between.
//  A: scores = [emb,h0]@attn_W.T + attn_b   (512 rows)
//     gh     = h0@W_hh.T + b_hh             (3072 rows; depends only on inputs)
//  B: softmax(scores) -> attn weights; attn_app = w @ enc   (blocks 0..31)
//  C: x = relu([emb,attn_app]@comb_W.T + comb_b)            (1024 rows)
//  D: GRU gates -> h1 (one wave per hidden index, 3 gi dots each)
// ---------------------------------------------------------------------------
__global__ void __launch_bounds__(256) frontend_kernel(
    const float* __restrict__ emb, const int* __restrict__ tok,
    const float* __restrict__ h0,
    const float* __restrict__ attn_W, const float* __restrict__ attn_b,
    const float* __restrict__ W_hh, const float* __restrict__ b_hh,
    const float* __restrict__ enc,
    const float* __restrict__ comb_W, const float* __restrict__ comb_b,
    const float* __restrict__ W_ih, const float* __restrict__ b_ih,
    float* __restrict__ scores, float* __restrict__ gh,
    float* __restrict__ attn_app, float* __restrict__ x,
    float* __restrict__ out_attn, float* __restrict__ out_h1)
{
    cg::grid_group grid = cg::this_grid();
    __shared__ float wlds[L];
    __shared__ float red[8];
    __shared__ float pl[8][33];

    int t = threadIdx.x, wid = t >> 6, lane = t & 63;
    int gw = blockIdx.x * 4 + wid;          // global wave id
    int NW = gridDim.x * 4;                 // total waves
    const float* a = emb + (size_t)tok[0] * E;

    // ---- Phase A: attention scores + gh --------------------------------
    for (int row = gw; row < L + 3 * H; row += NW) {
        float acc = 0.f;
        if (row < L) {
            const float* w = attn_W + (size_t)row * EH;
            #pragma unroll
            for (int r = 0; r < 2; ++r) {
                int idx = (r * 64 + lane) * 4;
                float4 av = *reinterpret_cast<const float4*>(a + idx);
                float4 wv = *reinterpret_cast<const float4*>(w + idx);
                acc += av.x * wv.x + av.y * wv.y + av.z * wv.z + av.w * wv.w;
            }
            #pragma unroll
            for (int r = 0; r < 4; ++r) {
                int idx = (r * 64 + lane) * 4;
                float4 bv = *reinterpret_cast<const float4*>(h0 + idx);
                float4 wv = *reinterpret_cast<const float4*>(w + E + idx);
                acc += bv.x * wv.x + bv.y * wv.y + bv.z * wv.z + bv.w * wv.w;
            }
            acc = wave_reduce_sum(acc);
            if (lane == 0) scores[row] = acc + attn_b[row];
        } else {
            int j = row - L;
            const float* w = W_hh + (size_t)j * H;
            #pragma unroll
            for (int r = 0; r < 4; ++r) {
                int idx = (r * 64 + lane) * 4;
                float4 av = *reinterpret_cast<const float4*>(h0 + idx);
                float4 wv = *reinterpret_cast<const float4*>(w + idx);
                acc += av.x * wv.x + av.y * wv.y + av.z * wv.z + av.w * wv.w;
            }
            acc = wave_reduce_sum(acc);
            if (lane == 0) gh[j] = acc + b_hh[j];
        }
    }
    grid.sync();

    // ---- Phase B: softmax + attn_applied (32 working blocks) -----------
    for (int b = blockIdx.x; b < H / 32; b += gridDim.x) {
        __syncthreads();
        float s0 = scores[t], s1 = scores[t + 256];
        float m = fmaxf(s0, s1);
        #pragma unroll
        for (int off = 32; off > 0; off >>= 1) m = fmaxf(m, __shfl_down(m, off, 64));
        if (lane == 0) red[wid] = m;
        __syncthreads();
        float M = fmaxf(fmaxf(red[0], red[1]), fmaxf(red[2], red[3]));
        float e0 = expf(s0 - M), e1 = expf(s1 - M);
        wlds[t] = e0; wlds[t + 256] = e1;
        float ps = wave_reduce_sum(e0 + e1);
        if (lane == 0) red[4 + wid] = ps;
        __syncthreads();
        float S = red[4] + red[5] + red[6] + red[7];
        float inv = 1.0f / S;
        wlds[t] *= inv; wlds[t + 256] *= inv;
        __syncthreads();
        if (b == 0) {
            out_attn[t] = wlds[t];
            out_attn[t + 256] = wlds[t + 256];
        }
        int hoff = t & 31, lc = t >> 5;
        int h = b * 32 + hoff;
        float acc = 0.f;
        #pragma unroll 4
        for (int l = lc * 64; l < lc * 64 + 64; ++l) acc += wlds[l] * enc[l * H + h];
        pl[lc][hoff] = acc;
        __syncthreads();
        if (t < 32) {
            float s = 0.f;
            #pragma unroll
            for (int c = 0; c < 8; ++c) s += pl[c][t];
            attn_app[b * 32 + t] = s;
        }
    }
    grid.sync();

    // ---- Phase C: combine + relu ---------------------------------------
    for (int row = gw; row < H; row += NW) {
        const float* w = comb_W + (size_t)row * EH;
        float acc = 0.f;
        #pragma unroll
        for (int r = 0; r < 2; ++r) {
            int idx = (r * 64 + lane) * 4;
            float4 av = *reinterpret_cast<const float4*>(a + idx);
            float4 wv = *reinterpret_cast<const float4*>(w + idx);
            acc += av.x * wv.x + av.y * wv.y + av.z * wv.z + av.w * wv.w;
        }
        #pragma unroll
        for (int r = 0; r < 4; ++r) {
            int idx = (r * 64 + lane) * 4;
            float4 bv = *reinterpret_cast<const float4*>(attn_app + idx);
            float4 wv = *reinterpret_cast<const float4*>(w + E + idx);
            acc += bv.x * wv.x + bv.y * wv.y + bv.z * wv.z + bv.w * wv.w;
        }
        acc = wave_reduce_sum(acc);
        if (lane == 0) x[row] = fmaxf(acc + comb_b[row], 0.f);
    }
    grid.sync();

    // ---- Phase D: GRU (one wave per hidden index, 3 gates) -------------
    for (int i = gw; i < H; i += NW) {
        const float* w0 = W_ih + (size_t)i * H;
        const float* w1 = W_ih + (size_t)(H + i) * H;
        const float* w2 = W_ih + (size_t)(2 * H + i) * H;
        float a0 = 0.f, a1 = 0.f, a2 = 0.f;
        #pragma unroll
        for (int r = 0; r < 4; ++r) {
            int idx = (r * 64 + lane) * 4;
            float4 xv = *reinterpret_cast<const float4*>(x + idx);
            float4 v0 = *reinterpret_cast<const float4*>(w0 + idx);
            float4 v1 = *reinterpret_cast<const float4*>(w1 + idx);
            float4 v2 = *reinterpret_cast<const float4*>(w2 + idx);
            a0 += xv.x * v0.x + xv.y * v0.y + xv.z * v0.z + xv.w * v0.w;
            a1 += xv.x * v1.x + xv.y * v1.y + xv.z * v1.z + xv.w * v1.w;
            a2 += xv.x * v2.x + xv.y * v2.y + xv.z * v2.z + xv.w * v2.w;
        }
        #pragma unroll
        for (int off = 32; off > 0; off >>= 1) {
            a0 += __shfl_down(a0, off, 64);
            a1 += __shfl_down(a1, off, 64);
            a2 += __shfl_down(a2, off, 64);
        }
        if (lane == 0) {
            float u0 = a0 + b_ih[i];
            float u1 = a1 + b_ih[H + i];
            float u2 = a2 + b_ih[2 * H + i];
            float v0 = gh[i], v1 = gh[H + i], v2 = gh[2 * H + i];
            float r = 1.f / (1.f + expf(-(u0 + v0)));
            float z = 1.f / (1.f + expf(-(u1 + v1)));
            float n = tanhf(u2 + r * v2);
            out_h1[i] = (1.f - z) * n + z * h0[i];
        }
    }
}

// ---------------------------------------------------------------------------
// Fallback (non-cooperative) front-end kernels — identical math, 4 launches.
// ---------------------------------------------------------------------------
__global__ void scores_gh_kernel(const float* __restrict__ emb, const int* __restrict__ tok,
                                 const float* __restrict__ h0,
                                 const float* __restrict__ attn_W, const float* __restrict__ attn_b,
                                 const float* __restrict__ W_hh, const float* __restrict__ b_hh,
                                 float* __restrict__ scores, float* __restrict__ gh)
{
    int wid  = threadIdx.x >> 6;
    int lane = threadIdx.x & 63;
    int row  = blockIdx.x * 4 + wid;
    float acc = 0.f;
    if (row < L) {
        const float* a = emb + (size_t)tok[0] * E;
        const float* w = attn_W + (size_t)row * EH;
        #pragma unroll
        for (int r = 0; r < 2; ++r) {
            int idx = (r * 64 + lane) * 4;
            float4 av = *reinterpret_cast<const float4*>(a + idx);
            float4 wv = *reinterpret_cast<const float4*>(w + idx);
            acc += av.x * wv.x + av.y * wv.y + av.z * wv.z + av.w * wv.w;
        }
        #pragma unroll
        for (int r = 0; r < 4; ++r) {
            int idx = (r * 64 + lane) * 4;
            float4 bv = *reinterpret_cast<const float4*>(h0 + idx);
            float4 wv = *reinterpret_cast<const float4*>(w + E + idx);
            acc += bv.x * wv.x + bv.y * wv.y + bv.z * wv.z + bv.w * wv.w;
        }
        acc = wave_reduce_sum(acc);
        if (lane == 0) scores[row] = acc + attn_b[row];
    } else {
        int j = row - L;
        const float* w = W_hh + (size_t)j * H;
        #pragma unroll
        for (int r = 0; r < 4; ++r) {
            int idx = (r * 64 + lane) * 4;
            float4 av = *reinterpret_cast<const float4*>(h0 + idx);
            float4 wv = *reinterpret_cast<const float4*>(w + idx);
            acc += av.x * wv.x + av.y * wv.y + av.z * wv.z + av.w * wv.w;
        }
        acc = wave_reduce_sum(acc);
        if (lane == 0) gh[j] = acc + b_hh[j];
    }
}

__global__ void softmax_attn_kernel(const float* __restrict__ scores,
                                    const float* __restrict__ enc,
                                    float* __restrict__ attn_app,
                                    float* __restrict__ attn_out)
{
    __shared__ float wlds[L];
    __shared__ float red[8];
    __shared__ float pl[8][33];
    int t = threadIdx.x;
    int wid = t >> 6, lane = t & 63;
    float s0 = scores[t], s1 = scores[t + 256];
    float m = fmaxf(s0, s1);
    #pragma unroll
    for (int off = 32; off > 0; off >>= 1) m = fmaxf(m, __shfl_down(m, off, 64));
    if (lane == 0) red[wid] = m;
    __syncthreads();
    float M = fmaxf(fmaxf(red[0], red[1]), fmaxf(red[2], red[3]));
    float e0 = expf(s0 - M), e1 = expf(s1 - M);
    wlds[t] = e0; wlds[t + 256] = e1;
    float ps = wave_reduce_sum(e0 + e1);
    if (lane == 0) red[4 + wid] = ps;
    __syncthreads();
    float S = red[4] + red[5] + red[6] + red[7];
    float inv = 1.0f / S;
    wlds[t] *= inv; wlds[t + 256] *= inv;
    __syncthreads();
    if (blockIdx.x == 0) {
        attn_out[t] = wlds[t];
        attn_out[t + 256] = wlds[t + 256];
    }
    int hoff = t & 31, lc = t >> 5;
    int h = blockIdx.x * 32 + hoff;
    float acc = 0.f;
    #pragma unroll 4
    for (int l = lc * 64; l < lc * 64 + 64; ++l) acc += wlds[l] * enc[l * H + h];
    pl[lc][hoff] = acc;
    __syncthreads();
    if (t < 32) {
        float s = 0.f;
        #pragma unroll
        for (int c = 0; c < 8; ++c) s += pl[c][t];
        attn_app[blockIdx.x * 32 + t] = s;
    }
}

__global__ void combine_kernel(const float* __restrict__ emb, const int* __restrict__ tok,
                               const float* __restrict__ Bvec,
                               const float* __restrict__ W, const float* __restrict__ bias,
                               float* __restrict__ out)
{
    int wid  = threadIdx.x >> 6;
    int lane = threadIdx.x & 63;
    int row  = blockIdx.x * 4 + wid;
    const float* a = emb + (size_t)tok[0] * E;
    const float* w = W + (size_t)row * EH;
    float acc = 0.f;
    #pragma unroll
    for (int r = 0; r < 2; ++r) {
        int idx = (r * 64 + lane) * 4;
        float4 av = *reinterpret_cast<const float4*>(a + idx);
        float4 wv = *reinterpret_cast<const float4*>(w + idx);
        acc += av.x * wv.x + av.y * wv.y + av.z * wv.z + av.w * wv.w;
    }
    #pragma unroll
    for (int r = 0; r < 4; ++r) {
        int idx = (r * 64 + lane) * 4;
        float4 bv = *reinterpret_cast<const float4*>(Bvec + idx);
        float4 wv = *reinterpret_cast<const float4*>(w + E + idx);
        acc += bv.x * wv.x + bv.y * wv.y + bv.z * wv.z + bv.w * wv.w;
    }
    acc = wave_reduce_sum(acc);
    if (lane == 0) out[row] = fmaxf(acc + bias[row], 0.f);
}

__global__ void gru_kernel(const float* __restrict__ x, const float* __restrict__ h0,
                           const float* __restrict__ W_ih, const float* __restrict__ b_ih,
                           const float* __restrict__ gh, float* __restrict__ h1_out)
{
    int lane = threadIdx.x & 63;
    int wv = threadIdx.x >> 6;
    int i = blockIdx.x * 4 + wv;
    const float* w0 = W_ih + (size_t)i * H;
    const float* w1 = W_ih + (size_t)(H + i) * H;
    const float* w2 = W_ih + (size_t)(2 * H + i) * H;
    float a0 = 0.f, a1 = 0.f, a2 = 0.f;
    #pragma unroll
    for (int r = 0; r < 4; ++r) {
        int idx = (r * 64 + lane) * 4;
        float4 xv = *reinterpret_cast<const float4*>(x + idx);
        float4 v0 = *reinterpret_cast<const float4*>(w0 + idx);
        float4 v1 = *reinterpret_cast<const float4*>(w1 + idx);
        float4 v2 = *reinterpret_cast<const float4*>(w2 + idx);
        a0 += xv.x * v0.x + xv.y * v0.y + xv.z * v0.z + xv.w * v0.w;
        a1 += xv.x * v1.x + xv.y * v1.y + xv.z * v1.z + xv.w * v1.w;
        a2 += xv.x * v2.x + xv.y * v2.y + xv.z * v2.z + xv.w * v2.w;
    }
    #pragma unroll
    for (int off = 32; off > 0; off >>= 1) {
        a0 += __shfl_down(a0, off, 64);
        a1 += __shfl_down(a1, off, 64);
        a2 += __shfl_down(a2, off, 64);
    }
    if (lane == 0) {
        float u0 = a0 + b_ih[i];
        float u1 = a1 + b_ih[H + i];
        float u2 = a2 + b_ih[2 * H + i];
        float v0 = gh[i], v1 = gh[H + i], v2 = gh[2 * H + i];
        float r = 1.f / (1.f + expf(-(u0 + v0)));
        float z = 1.f / (1.f + expf(-(u1 + v1)));
        float n = tanhf(u2 + r * v2);
        h1_out[i] = (1.f - z) * n + z * h0[i];
    }
}

// ---------------------------------------------------------------------------
// Output projection: one wave per vocab row, 8 rows/block (512 thr).
// Writes raw logits into d_out plus per-block (max, sumexp) partials.
// ---------------------------------------------------------------------------
__global__ void outproj_kernel(const float* __restrict__ h1, const float* __restrict__ out_W,
                               const float* __restrict__ out_b, float* __restrict__ logits,
                               float* __restrict__ mws, float* __restrict__ sws)
{
    __shared__ float lg[8];
    int wid = threadIdx.x >> 6, lane = threadIdx.x & 63;
    int v = blockIdx.x * 8 + wid;
    float logit = -INFINITY;
    if (v < V) {
        const float* w = out_W + (size_t)v * H;
        float acc = 0.f;
        #pragma unroll
        for (int r = 0; r < 4; ++r) {
            int idx = (r * 64 + lane) * 4;
            float4 a = *reinterpret_cast<const float4*>(h1 + idx);
            float4 b = *reinterpret_cast<const float4*>(w + idx);
            acc += a.x * b.x + a.y * b.y + a.z * b.z + a.w * b.w;
        }
        acc = wave_reduce_sum(acc);
        logit = acc + out_b[v];
        if (lane == 0) logits[v] = logit;
    }
    if (lane == 0) lg[wid] = logit;
    __syncthreads();
    if (threadIdx.x == 0) {
        float m = lg[0];
        #pragma unroll
        for (int k = 1; k < 8; ++k) m = fmaxf(m, lg[k]);
        float s = 0.f;
        #pragma unroll
        for (int k = 0; k < 8; ++k) s += expf(lg[k] - m);   // exp(-inf)=0 for tail
        mws[blockIdx.x] = m;
        sws[blockIdx.x] = s;
    }
}

// Final pass: every block redundantly reduces the (m,s) partials (L2-resident)
// to the logsumexp, then subtracts in place over its 1024-element slice.
__global__ void logp_kernel(const float* __restrict__ mws, const float* __restrict__ sws,
                            int nblk, float* __restrict__ out)
{
    __shared__ float mr[4], sr[4];
    __shared__ float lse_s;
    int t = threadIdx.x;
    float m = -INFINITY, s = 0.f;
    for (int b = t; b < nblk; b += 256) {
        float mb = mws[b], sb = sws[b];
        float M = fmaxf(m, mb);
        s = s * expf(m - M) + sb * expf(mb - M);
        m = M;
    }
    #pragma unroll
    for (int off = 32; off > 0; off >>= 1) {
        float mo = __shfl_down(m, off, 64);
        float so = __shfl_down(s, off, 64);
        float M = fmaxf(m, mo);
        s = s * expf(m - M) + so * expf(mo - M);
        m = M;
    }
    if ((t & 63) == 0) { mr[t >> 6] = m; sr[t >> 6] = s; }
    __syncthreads();
    if (t == 0) {
        float M = mr[0], S = sr[0];
        #pragma unroll
        for (int k = 1; k < 4; ++k) {
            float Mn = fmaxf(M, mr[k]);
            S = S * expf(M - Mn) + sr[k] * expf(mr[k] - Mn);
            M = Mn;
        }
        lse_s = M + logf(S);
    }
    __syncthreads();
    float lse = lse_s;
    int base = blockIdx.x * 1024 + t;
    #pragma unroll
    for (int k = 0; k < 4; ++k) {
        int v = base + k * 256;
        if (v < V) out[v] -= lse;
    }
}

extern "C" void kernel_launch(void* const* d_in, const int* in_sizes, int n_in,
                              void* d_out, int out_size, void* d_ws, size_t ws_size,
                              hipStream_t stream) {
    const int*   tok    = (const int*)  d_in[0];
    const float* hidden = (const float*)d_in[1];
    const float* enc    = (const float*)d_in[2];
    const float* emb    = (const float*)d_in[3];
    const float* attn_W = (const float*)d_in[4];
    const float* attn_b = (const float*)d_in[5];
    const float* comb_W = (const float*)d_in[6];
    const float* comb_b = (const float*)d_in[7];
    const float* W_ih   = (const float*)d_in[8];
    const float* W_hh   = (const float*)d_in[9];
    const float* b_ih   = (const float*)d_in[10];
    const float* b_hh   = (const float*)d_in[11];
    const float* out_W  = (const float*)d_in[12];
    const float* out_b  = (const float*)d_in[13];

    float* out = (float*)d_out;
    float* ws  = (float*)d_ws;

    // outputs (concatenated flat in return order)
    float* out_logp = out;           // 50257
    float* out_h1   = out + V;       // 1024
    float* out_attn = out + V + H;   // 512

    // workspace layout (float offsets, 16B-aligned); total ~74 KB
    float* scores   = ws + 0;        // 512
    float* attn_app = ws + 512;      // 1024
    float* x        = ws + 1536;     // 1024
    float* gh       = ws + 2560;     // 3072
    float* mws      = ws + 5632;     // 6283
    float* sws      = ws + 11968;    // 6283 (ends 18251)

    // --- front-end: cooperative fused kernel, fallback to 4 launches ----
    int nb = 0;
    hipError_t occ_err = hipOccupancyMaxActiveBlocksPerMultiprocessor(
        &nb, (const void*)frontend_kernel, 256, 0);
    int grid = (occ_err == hipSuccess && nb >= 1) ? nb * 256 : 256;
    if (grid > 512) grid = 512;
    if (grid < 32)  grid = 32;

    void* args[] = {
        (void*)&emb, (void*)&tok, (void*)&hidden,
        (void*)&attn_W, (void*)&attn_b,
        (void*)&W_hh, (void*)&b_hh,
        (void*)&enc,
        (void*)&comb_W, (void*)&comb_b,
        (void*)&W_ih, (void*)&b_ih,
        (void*)&scores, (void*)&gh, (void*)&attn_app, (void*)&x,
        (void*)&out_attn, (void*)&out_h1
    };
    hipError_t cerr = hipLaunchCooperativeKernel(
        (const void*)frontend_kernel, dim3(grid), dim3(256), args, 0, stream);

    if (cerr != hipSuccess) {
        // Fallback: identical math as 4 sequential launches.
        scores_gh_kernel<<<(L + 3 * H) / 4, 256, 0, stream>>>(
            emb, tok, hidden, attn_W, attn_b, W_hh, b_hh, scores, gh);
        softmax_attn_kernel<<<H / 32, 256, 0, stream>>>(scores, enc, attn_app, out_attn);
        combine_kernel<<<H / 4, 256, 0, stream>>>(emb, tok, attn_app, comb_W, comb_b, x);
        gru_kernel<<<H / 4, 256, 0, stream>>>(x, hidden, W_ih, b_ih, gh, out_h1);
    }

    // --- output projection + log_softmax --------------------------------
    int nblk = (V + 7) / 8;          // 6283
    outproj_kernel<<<nblk, 512, 0, stream>>>(out_h1, out_W, out_b, out_logp, mws, sws);
    logp_kernel<<<(V + 1023) / 1024, 256, 0, stream>>>(mws, sws, nblk, out_logp);
}

// Round 8
// 369.656 us; speedup vs baseline: 1.5449x; 1.5449x over previous
//
#include <hip/hip_runtime.h>
#include <hip/hip_bf16.h>
#include <math.h>

// Problem constants
#define V 50257
#define E 512
#define H 1024
#define L 512
#define EH 1536

typedef float vfloat4 __attribute__((ext_vector_type(4)));

__device__ __forceinline__ vfloat4 ntload4(const float* p) {
    return __builtin_nontemporal_load(reinterpret_cast<const vfloat4*>(p));
}

__device__ __forceinline__ float wave_reduce_sum(float v) {
    #pragma unroll
    for (int off = 32; off > 0; off >>= 1) v += __shfl_down(v, off, 64);
    return v;
}

// Phase 1: rows 0..511    -> scores = [emb,h0]@attn_W.T + attn_b
//          rows 512..3583 -> gh = h0@W_hh.T + b_hh  (depends only on inputs)
// One wave per row, 4 waves/block. Weight loads non-temporal (read-once).
__global__ void __launch_bounds__(256) scores_gh_kernel(
    const float* __restrict__ emb, const int* __restrict__ tok,
    const float* __restrict__ h0,
    const float* __restrict__ attn_W, const float* __restrict__ attn_b,
    const float* __restrict__ W_hh, const float* __restrict__ b_hh,
    float* __restrict__ scores, float* __restrict__ gh)
{
    int wid  = threadIdx.x >> 6;
    int lane = threadIdx.x & 63;
    int row  = blockIdx.x * 4 + wid;
    float acc = 0.f;
    if (row < L) {
        const float* a = emb + (size_t)tok[0] * E;
        const float* w = attn_W + (size_t)row * EH;
        #pragma unroll
        for (int r = 0; r < 2; ++r) {
            int idx = (r * 64 + lane) * 4;
            float4 av = *reinterpret_cast<const float4*>(a + idx);
            vfloat4 wv = ntload4(w + idx);
            acc += av.x * wv.x + av.y * wv.y + av.z * wv.z + av.w * wv.w;
        }
        #pragma unroll
        for (int r = 0; r < 4; ++r) {
            int idx = (r * 64 + lane) * 4;
            float4 bv = *reinterpret_cast<const float4*>(h0 + idx);
            vfloat4 wv = ntload4(w + E + idx);
            acc += bv.x * wv.x + bv.y * wv.y + bv.z * wv.z + bv.w * wv.w;
        }
        acc = wave_reduce_sum(acc);
        if (lane == 0) scores[row] = acc + attn_b[row];
    } else {
        int j = row - L;
        const float* w = W_hh + (size_t)j * H;
        #pragma unroll
        for (int r = 0; r < 4; ++r) {
            int idx = (r * 64 + lane) * 4;
            float4 av = *reinterpret_cast<const float4*>(h0 + idx);
            vfloat4 wv = ntload4(w + idx);
            acc += av.x * wv.x + av.y * wv.y + av.z * wv.z + av.w * wv.w;
        }
        acc = wave_reduce_sum(acc);
        if (lane == 0) gh[j] = acc + b_hh[j];
    }
}

// Softmax over 512 scores (each block redundantly computes it — 2KB, trivial),
// then each block computes 32 columns of attn_applied = w @ enc [512,1024].
// Block 0 additionally writes the normalized attention weights output.
__global__ void __launch_bounds__(256) softmax_attn_kernel(
    const float* __restrict__ scores, const float* __restrict__ enc,
    float* __restrict__ attn_app, float* __restrict__ attn_out)
{
    __shared__ float wlds[L];
    __shared__ float red[8];
    __shared__ float pl[8][33];
    int t = threadIdx.x;
    int wid = t >> 6, lane = t & 63;
    float s0 = scores[t], s1 = scores[t + 256];
    float m = fmaxf(s0, s1);
    #pragma unroll
    for (int off = 32; off > 0; off >>= 1) m = fmaxf(m, __shfl_down(m, off, 64));
    if (lane == 0) red[wid] = m;
    __syncthreads();
    float M = fmaxf(fmaxf(red[0], red[1]), fmaxf(red[2], red[3]));
    float e0 = expf(s0 - M), e1 = expf(s1 - M);
    wlds[t] = e0; wlds[t + 256] = e1;
    float ps = wave_reduce_sum(e0 + e1);
    if (lane == 0) red[4 + wid] = ps;
    __syncthreads();
    float S = red[4] + red[5] + red[6] + red[7];
    float inv = 1.0f / S;
    wlds[t] *= inv; wlds[t + 256] *= inv;
    __syncthreads();
    if (blockIdx.x == 0) {
        attn_out[t] = wlds[t];
        attn_out[t + 256] = wlds[t + 256];
    }
    int hoff = t & 31, lc = t >> 5;
    int h = blockIdx.x * 32 + hoff;
    float acc = 0.f;
    #pragma unroll 4
    for (int l = lc * 64; l < lc * 64 + 64; ++l) acc += wlds[l] * enc[l * H + h];
    pl[lc][hoff] = acc;
    __syncthreads();
    if (t < 32) {
        float s = 0.f;
        #pragma unroll
        for (int c = 0; c < 8; ++c) s += pl[c][t];
        attn_app[blockIdx.x * 32 + t] = s;
    }
}

// combine + relu: x = relu(cat([emb_row, attn_applied]) @ comb_W.T + comb_b)
__global__ void __launch_bounds__(256) combine_kernel(
    const float* __restrict__ emb, const int* __restrict__ tok,
    const float* __restrict__ Bvec,
    const float* __restrict__ W, const float* __restrict__ bias,
    float* __restrict__ out)
{
    int wid  = threadIdx.x >> 6;
    int lane = threadIdx.x & 63;
    int row  = blockIdx.x * 4 + wid;
    const float* a = emb + (size_t)tok[0] * E;
    const float* w = W + (size_t)row * EH;
    float acc = 0.f;
    #pragma unroll
    for (int r = 0; r < 2; ++r) {
        int idx = (r * 64 + lane) * 4;
        float4 av = *reinterpret_cast<const float4*>(a + idx);
        vfloat4 wv = ntload4(w + idx);
        acc += av.x * wv.x + av.y * wv.y + av.z * wv.z + av.w * wv.w;
    }
    #pragma unroll
    for (int r = 0; r < 4; ++r) {
        int idx = (r * 64 + lane) * 4;
        float4 bv = *reinterpret_cast<const float4*>(Bvec + idx);
        vfloat4 wv = ntload4(w + E + idx);
        acc += bv.x * wv.x + bv.y * wv.y + bv.z * wv.z + bv.w * wv.w;
    }
    acc = wave_reduce_sum(acc);
    if (lane == 0) out[row] = fmaxf(acc + bias[row], 0.f);
}

// GRU: one wave per hidden index (4 waves/block); each wave does the 3 gi
// dots (x loaded once, 3 accumulator chains); gh precomputed in phase 1.
__global__ void __launch_bounds__(256) gru_kernel(
    const float* __restrict__ x, const float* __restrict__ h0,
    const float* __restrict__ W_ih, const float* __restrict__ b_ih,
    const float* __restrict__ gh, float* __restrict__ h1_out)
{
    int lane = threadIdx.x & 63;
    int wv = threadIdx.x >> 6;
    int i = blockIdx.x * 4 + wv;
    const float* w0 = W_ih + (size_t)i * H;
    const float* w1 = W_ih + (size_t)(H + i) * H;
    const float* w2 = W_ih + (size_t)(2 * H + i) * H;
    float a0 = 0.f, a1 = 0.f, a2 = 0.f;
    #pragma unroll
    for (int r = 0; r < 4; ++r) {
        int idx = (r * 64 + lane) * 4;
        float4 xv = *reinterpret_cast<const float4*>(x + idx);
        vfloat4 v0 = ntload4(w0 + idx);
        vfloat4 v1 = ntload4(w1 + idx);
        vfloat4 v2 = ntload4(w2 + idx);
        a0 += xv.x * v0.x + xv.y * v0.y + xv.z * v0.z + xv.w * v0.w;
        a1 += xv.x * v1.x + xv.y * v1.y + xv.z * v1.z + xv.w * v1.w;
        a2 += xv.x * v2.x + xv.y * v2.y + xv.z * v2.z + xv.w * v2.w;
    }
    #pragma unroll
    for (int off = 32; off > 0; off >>= 1) {
        a0 += __shfl_down(a0, off, 64);
        a1 += __shfl_down(a1, off, 64);
        a2 += __shfl_down(a2, off, 64);
    }
    if (lane == 0) {
        float u0 = a0 + b_ih[i];
        float u1 = a1 + b_ih[H + i];
        float u2 = a2 + b_ih[2 * H + i];
        float v0 = gh[i], v1 = gh[H + i], v2 = gh[2 * H + i];
        float r = 1.f / (1.f + expf(-(u0 + v0)));
        float z = 1.f / (1.f + expf(-(u1 + v1)));
        float n = tanhf(u2 + r * v2);
        h1_out[i] = (1.f - z) * n + z * h0[i];
    }
}

// Output projection: one wave per vocab row, 8 rows/block (512 thr).
// Writes raw logits into d_out plus per-block (max, sumexp) partials.
// out_W streamed non-temporally (206 MB read-once).
__global__ void __launch_bounds__(512) outproj_kernel(
    const float* __restrict__ h1, const float* __restrict__ out_W,
    const float* __restrict__ out_b, float* __restrict__ logits,
    float* __restrict__ mws, float* __restrict__ sws)
{
    __shared__ float lg[8];
    int wid = threadIdx.x >> 6, lane = threadIdx.x & 63;
    int v = blockIdx.x * 8 + wid;
    float logit = -INFINITY;
    if (v < V) {
        const float* w = out_W + (size_t)v * H;
        float acc = 0.f;
        #pragma unroll
        for (int r = 0; r < 4; ++r) {
            int idx = (r * 64 + lane) * 4;
            float4 a = *reinterpret_cast<const float4*>(h1 + idx);
            vfloat4 b = ntload4(w + idx);
            acc += a.x * b.x + a.y * b.y + a.z * b.z + a.w * b.w;
        }
        acc = wave_reduce_sum(acc);
        logit = acc + out_b[v];
        if (lane == 0) logits[v] = logit;
    }
    if (lane == 0) lg[wid] = logit;
    __syncthreads();
    if (threadIdx.x == 0) {
        float m = lg[0];
        #pragma unroll
        for (int k = 1; k < 8; ++k) m = fmaxf(m, lg[k]);
        float s = 0.f;
        #pragma unroll
        for (int k = 0; k < 8; ++k) s += expf(lg[k] - m);   // exp(-inf)=0 for tail
        mws[blockIdx.x] = m;
        sws[blockIdx.x] = s;
    }
}

// Final pass: every block redundantly reduces the (m,s) partials (L2-resident)
// to the logsumexp, then subtracts in place over its 1024-element slice.
__global__ void __launch_bounds__(256) logp_kernel(
    const float* __restrict__ mws, const float* __restrict__ sws,
    int nblk, float* __restrict__ out)
{
    __shared__ float mr[4], sr[4];
    __shared__ float lse_s;
    int t = threadIdx.x;
    float m = -INFINITY, s = 0.f;
    for (int b = t; b < nblk; b += 256) {
        float mb = mws[b], sb = sws[b];
        float M = fmaxf(m, mb);
        s = s * expf(m - M) + sb * expf(mb - M);
        m = M;
    }
    #pragma unroll
    for (int off = 32; off > 0; off >>= 1) {
        float mo = __shfl_down(m, off, 64);
        float so = __shfl_down(s, off, 64);
        float M = fmaxf(m, mo);
        s = s * expf(m - M) + so * expf(mo - M);
        m = M;
    }
    if ((t & 63) == 0) { mr[t >> 6] = m; sr[t >> 6] = s; }
    __syncthreads();
    if (t == 0) {
        float M = mr[0], S = sr[0];
        #pragma unroll
        for (int k = 1; k < 4; ++k) {
            float Mn = fmaxf(M, mr[k]);
            S = S * expf(M - Mn) + sr[k] * expf(mr[k] - Mn);
            M = Mn;
        }
        lse_s = M + logf(S);
    }
    __syncthreads();
    float lse = lse_s;
    int base = blockIdx.x * 1024 + t;
    #pragma unroll
    for (int k = 0; k < 4; ++k) {
        int v = base + k * 256;
        if (v < V) out[v] -= lse;
    }
}

extern "C" void kernel_launch(void* const* d_in, const int* in_sizes, int n_in,
                              void* d_out, int out_size, void* d_ws, size_t ws_size,
                              hipStream_t stream) {
    const int*   tok    = (const int*)  d_in[0];
    const float* hidden = (const float*)d_in[1];
    const float* enc    = (const float*)d_in[2];
    const float* emb    = (const float*)d_in[3];
    const float* attn_W = (const float*)d_in[4];
    const float* attn_b = (const float*)d_in[5];
    const float* comb_W = (const float*)d_in[6];
    const float* comb_b = (const float*)d_in[7];
    const float* W_ih   = (const float*)d_in[8];
    const float* W_hh   = (const float*)d_in[9];
    const float* b_ih   = (const float*)d_in[10];
    const float* b_hh   = (const float*)d_in[11];
    const float* out_W  = (const float*)d_in[12];
    const float* out_b  = (const float*)d_in[13];

    float* out = (float*)d_out;
    float* ws  = (float*)d_ws;

    // outputs (concatenated flat in return order)
    float* out_logp = out;           // 50257
    float* out_h1   = out + V;       // 1024
    float* out_attn = out + V + H;   // 512

    // workspace layout (float offsets, 16B-aligned); total ~74 KB
    float* scores   = ws + 0;        // 512
    float* attn_app = ws + 512;      // 1024
    float* x        = ws + 1536;     // 1024
    float* gh       = ws + 2560;     // 3072
    float* mws      = ws + 5632;     // 6283
    float* sws      = ws + 11968;    // 6283 (ends 18251)

    // 1. fused: attention scores + GRU gh (both depend only on inputs)
    scores_gh_kernel<<<(L + 3 * H) / 4, 256, 0, stream>>>(
        emb, tok, hidden, attn_W, attn_b, W_hh, b_hh, scores, gh);
    // 2. softmax + attn_applied (+ write attn_weights output)
    softmax_attn_kernel<<<H / 32, 256, 0, stream>>>(scores, enc, attn_app, out_attn);
    // 3. combine + relu
    combine_kernel<<<H / 4, 256, 0, stream>>>(emb, tok, attn_app, comb_W, comb_b, x);
    // 4. GRU step -> h1 (written straight into d_out's h1 slot)
    gru_kernel<<<H / 4, 256, 0, stream>>>(x, hidden, W_ih, b_ih, gh, out_h1);
    // 5. output projection: logits into d_out + per-block lse partials
    int nblk = (V + 7) / 8;          // 6283
    outproj_kernel<<<nblk, 512, 0, stream>>>(out_h1, out_W, out_b, out_logp, mws, sws);
    // 6. logsumexp (redundant per block) + in-place subtract
    logp_kernel<<<(V + 1023) / 1024, 256, 0, stream>>>(mws, sws, nblk, out_logp);
}